// Round 1
// baseline (1111.956 us; speedup 1.0000x reference)
//
#include <hip/hip_runtime.h>
#include <stdint.h>

#define NPTS 16384
#define BATCH 16
#define FPS_N 512
#define NANCH 50
#define TOPK 4
#define NBH 128
#define BALLK 1000

#define FT 1024
#define FPPT (NPTS / FT)   // 16 points per thread

__device__ __forceinline__ uint32_t f2key(float f) {
  // monotone float->uint transform (handles tiny negative d2 from cancellation)
  uint32_t u = __float_as_uint(f);
  return (u & 0x80000000u) ? ~u : (u | 0x80000000u);
}

// ---------------- FPS: one block per batch, 511 serial argmax steps ----------
__global__ __launch_bounds__(FT) void fps_kernel(const float* __restrict__ pts,
                                                 int* __restrict__ fps_idx) {
  const int b = blockIdx.x;
  const int tid = threadIdx.x;
  const float* __restrict__ px = pts + (size_t)b * 3 * NPTS;
  const float* __restrict__ py = px + NPTS;
  const float* __restrict__ pz = py + NPTS;

  float x[FPPT], y[FPPT], z[FPPT], dist[FPPT];
#pragma unroll
  for (int k = 0; k < FPPT; ++k) {
    const int i = tid + k * FT;
    x[k] = px[i]; y[k] = py[i]; z[k] = pz[i];
    dist[k] = 1e10f;
  }
  __shared__ unsigned long long waveres[2][16];  // parity double-buffer -> 1 barrier/step
  if (tid == 0) fps_idx[b * FPS_N] = 0;
  // first centroid = point 0 (broadcast global load)
  float bx = px[0], by = py[0], bz = pz[0];

  for (int step = 1; step < FPS_N; ++step) {
    unsigned long long best = 0ULL;
#pragma unroll
    for (int k = 0; k < FPPT; ++k) {
      // match jnp: (x-c)**2 summed over 3, no fma contraction
      const float dx = __fsub_rn(x[k], bx);
      const float dy = __fsub_rn(y[k], by);
      const float dz = __fsub_rn(z[k], bz);
      const float d = __fadd_rn(__fadd_rn(__fmul_rn(dx, dx), __fmul_rn(dy, dy)),
                                __fmul_rn(dz, dz));
      const float dk = fminf(dist[k], d);
      dist[k] = dk;
      // max-reduce key: dist bits high (dist>=0), ~idx low (ties -> lowest idx)
      const unsigned long long key =
          ((unsigned long long)__float_as_uint(dk) << 32) |
          (uint32_t)(~(uint32_t)(tid + k * FT));
      best = best < key ? key : best;
    }
#pragma unroll
    for (int off = 32; off > 0; off >>= 1) {
      const unsigned long long o = __shfl_xor(best, off, 64);
      best = best < o ? o : best;
    }
    if ((tid & 63) == 0) waveres[step & 1][tid >> 6] = best;
    __syncthreads();
    unsigned long long g = waveres[step & 1][0];
#pragma unroll
    for (int w = 1; w < 16; ++w) {
      const unsigned long long o = waveres[step & 1][w];
      g = g < o ? o : g;
    }
    const uint32_t widx = ~(uint32_t)g;
    if (tid == 0) fps_idx[b * FPS_N + step] = (int)widx;
    // broadcast centroid via (L2-cached) global load; avoids 2nd barrier and
    // avoids runtime-indexing the register arrays (scratch trap)
    bx = px[widx]; by = py[widx]; bz = pz[widx];
  }
}

// ---------------- ball-radius counts for the 50 anchors ---------------------
__global__ __launch_bounds__(256) void count_kernel(const float* __restrict__ pts,
                                                    const int* __restrict__ fps_idx,
                                                    int* __restrict__ counts) {
  const int b = blockIdx.y, a = blockIdx.x;
  const int tid = threadIdx.x;
  const float* __restrict__ px = pts + (size_t)b * 3 * NPTS;
  const float* __restrict__ py = px + NPTS;
  const float* __restrict__ pz = py + NPTS;
  const int aidx = fps_idx[b * FPS_N + a];
  const float ax = px[aidx], ay = py[aidx], az = pz[aidx];
  const float asum = __fadd_rn(__fadd_rn(__fmul_rn(ax, ax), __fmul_rn(ay, ay)),
                               __fmul_rn(az, az));
  const float R2 = (float)(0.4 * 0.4);  // double product then cast, matches jax weak-type f32(0.16)
  int cnt = 0;
  for (int i = tid; i < NPTS; i += 256) {
    const float X = px[i], Y = py[i], Z = pz[i];
    const float dot = __fadd_rn(__fadd_rn(__fmul_rn(ax, X), __fmul_rn(ay, Y)),
                                __fmul_rn(az, Z));
    const float psum = __fadd_rn(__fadd_rn(__fmul_rn(X, X), __fmul_rn(Y, Y)),
                                 __fmul_rn(Z, Z));
    const float d = __fadd_rn(__fadd_rn(__fmul_rn(-2.0f, dot), asum), psum);
    cnt += (d < R2) ? 1 : 0;
  }
#pragma unroll
  for (int off = 32; off > 0; off >>= 1) cnt += __shfl_xor(cnt, off, 64);
  __shared__ int ws[4];
  if ((tid & 63) == 0) ws[tid >> 6] = cnt;
  __syncthreads();
  if (tid == 0) {
    int c = ws[0] + ws[1] + ws[2] + ws[3];
    counts[b * NANCH + a] = c < BALLK ? c : BALLK;
  }
}

// ---------------- top-4 anchors by count (ties -> lowest anchor index) ------
__global__ void top4_kernel(const int* __restrict__ counts,
                            const int* __restrict__ fps_idx,
                            int* __restrict__ top4pt) {
  const int b = threadIdx.x;
  if (b >= BATCH) return;
  unsigned long long used = 0ULL;
  for (int r = 0; r < TOPK; ++r) {
    int bestc = -1, besta = 0;
    for (int a = 0; a < NANCH; ++a) {
      if (used & (1ULL << a)) continue;
      const int c = counts[b * NANCH + a];
      if (c > bestc) { bestc = c; besta = a; }   // strict > keeps lowest index on ties
    }
    used |= 1ULL << besta;
    top4pt[b * TOPK + r] = fps_idx[b * FPS_N + besta];  // store point index directly
  }
}

// ---------------- 128-NN per selected anchor, in sorted order ---------------
#define KT 1024
#define KPPT (NPTS / KT)  // 16

__global__ __launch_bounds__(KT) void knn_kernel(const float* __restrict__ pts,
                                                 const int* __restrict__ top4pt,
                                                 int* __restrict__ nn_idx) {
  const int b = blockIdx.y, j = blockIdx.x;
  const int tid = threadIdx.x;
  const float* __restrict__ px = pts + (size_t)b * 3 * NPTS;
  const float* __restrict__ py = px + NPTS;
  const float* __restrict__ pz = py + NPTS;
  const int aidx = top4pt[b * TOPK + j];
  const float ax = px[aidx], ay = py[aidx], az = pz[aidx];
  const float asum = __fadd_rn(__fadd_rn(__fmul_rn(ax, ax), __fmul_rn(ay, ay)),
                               __fmul_rn(az, az));
  unsigned long long key[KPPT];
#pragma unroll
  for (int k = 0; k < KPPT; ++k) {
    const int i = tid + k * KT;
    const float X = px[i], Y = py[i], Z = pz[i];
    const float dot = __fadd_rn(__fadd_rn(__fmul_rn(ax, X), __fmul_rn(ay, Y)),
                                __fmul_rn(az, Z));
    const float psum = __fadd_rn(__fadd_rn(__fmul_rn(X, X), __fmul_rn(Y, Y)),
                                 __fmul_rn(Z, Z));
    const float d = __fadd_rn(__fadd_rn(__fmul_rn(-2.0f, dot), asum), psum);
    key[k] = ((unsigned long long)f2key(d) << 32) | (uint32_t)i;  // asc dist, ties asc idx
  }
  __shared__ unsigned long long waveres[2][16];
  for (int t = 0; t < NBH; ++t) {
    unsigned long long m = key[0];
#pragma unroll
    for (int k = 1; k < KPPT; ++k) m = key[k] < m ? key[k] : m;
#pragma unroll
    for (int off = 32; off > 0; off >>= 1) {
      const unsigned long long o = __shfl_xor(m, off, 64);
      m = o < m ? o : m;
    }
    if ((tid & 63) == 0) waveres[t & 1][tid >> 6] = m;
    __syncthreads();
    unsigned long long g = waveres[t & 1][0];
#pragma unroll
    for (int w = 1; w < 16; ++w) {
      const unsigned long long o = waveres[t & 1][w];
      g = o < g ? o : g;
    }
    if (tid == 0) nn_idx[(b * TOPK + j) * NBH + t] = (int)(uint32_t)g;
#pragma unroll
    for (int k = 0; k < KPPT; ++k)
      if (key[k] == g) key[k] = ~0ULL;  // remove winner (unique low bits)
  }
}

// ---------------- final gather: [roi, roi, fps_pts] -> out [16,1536,3] ------
__global__ __launch_bounds__(512) void gather_kernel(const float* __restrict__ pts,
                                                     const int* __restrict__ nn_idx,
                                                     const int* __restrict__ fps_idx,
                                                     float* __restrict__ out) {
  const int b = blockIdx.x, t = threadIdx.x;
  const float* __restrict__ px = pts + (size_t)b * 3 * NPTS;
  const float* __restrict__ py = px + NPTS;
  const float* __restrict__ pz = py + NPTS;
  for (int s = t; s < 1536; s += 512) {
    int src;
    if (s < 1024) src = nn_idx[b * 512 + (s & 511)];      // roi1 and roi2 identical
    else          src = fps_idx[b * FPS_N + (s - 1024)];
    float* o = out + ((size_t)b * 1536 + s) * 3;
    o[0] = px[src]; o[1] = py[src]; o[2] = pz[src];
  }
}

extern "C" void kernel_launch(void* const* d_in, const int* in_sizes, int n_in,
                              void* d_out, int out_size, void* d_ws, size_t ws_size,
                              hipStream_t stream) {
  const float* pts = (const float*)d_in[0];   // [16, 3, 16384]
  float* out = (float*)d_out;                 // [16, 1536, 3]
  char* ws = (char*)d_ws;
  int* fps_idx = (int*)(ws);            // 16*512*4 = 32768 B
  int* counts  = (int*)(ws + 32768);    // 16*50*4  =  3200 B
  int* top4pt  = (int*)(ws + 40960);    // 16*4*4   =   256 B
  int* nn_idx  = (int*)(ws + 49152);    // 16*512*4 = 32768 B

  fps_kernel<<<dim3(BATCH), dim3(FT), 0, stream>>>(pts, fps_idx);
  count_kernel<<<dim3(NANCH, BATCH), dim3(256), 0, stream>>>(pts, fps_idx, counts);
  top4_kernel<<<dim3(1), dim3(64), 0, stream>>>(counts, fps_idx, top4pt);
  knn_kernel<<<dim3(TOPK, BATCH), dim3(KT), 0, stream>>>(pts, top4pt, nn_idx);
  gather_kernel<<<dim3(BATCH), dim3(512), 0, stream>>>(pts, nn_idx, fps_idx, out);
}

// Round 2
// 1056.188 us; speedup vs baseline: 1.0528x; 1.0528x over previous
//
#include <hip/hip_runtime.h>
#include <stdint.h>

#define NPTS 16384
#define BATCH 16
#define FPS_N 512
#define NANCH 50
#define TOPK 4
#define NBH 128
#define BALLK 1000

#define FT 1024
#define FPPT (NPTS / FT)   // 16 points per thread

// DPP control codes (within-16-lane row ops)
#define CTRL_XOR1 0xB1   // quad_perm [1,0,3,2]
#define CTRL_XOR2 0x4E   // quad_perm [2,3,0,1]
#define CTRL_ROR4 0x124  // row_ror:4
#define CTRL_ROR8 0x128  // row_ror:8

// u64 max-combine with a DPP-shuffled copy (old=src -> masked lanes identity)
#define DPP_MAX64(v, CTRL) do {                                                   \
  unsigned int _lo = (unsigned int)(v);                                           \
  unsigned int _hi = (unsigned int)((v) >> 32);                                   \
  unsigned int _slo = (unsigned int)__builtin_amdgcn_update_dpp((int)_lo, (int)_lo, CTRL, 0xf, 0xf, false); \
  unsigned int _shi = (unsigned int)__builtin_amdgcn_update_dpp((int)_hi, (int)_hi, CTRL, 0xf, 0xf, false); \
  unsigned long long _o = (((unsigned long long)_shi) << 32) | _slo;              \
  if (_o > (v)) (v) = _o;                                                         \
} while (0)

#define DPP_MIN64(v, CTRL) do {                                                   \
  unsigned int _lo = (unsigned int)(v);                                           \
  unsigned int _hi = (unsigned int)((v) >> 32);                                   \
  unsigned int _slo = (unsigned int)__builtin_amdgcn_update_dpp((int)_lo, (int)_lo, CTRL, 0xf, 0xf, false); \
  unsigned int _shi = (unsigned int)__builtin_amdgcn_update_dpp((int)_hi, (int)_hi, CTRL, 0xf, 0xf, false); \
  unsigned long long _o = (((unsigned long long)_shi) << 32) | _slo;              \
  if (_o < (v)) (v) = _o;                                                         \
} while (0)

// xor-16 via ds_swizzle (valid within each 32-lane half; xor16 stays in-half)
#define SWZ16_MAX64(v) do {                                                       \
  unsigned int _lo = (unsigned int)(v), _hi = (unsigned int)((v) >> 32);          \
  unsigned int _slo = (unsigned int)__builtin_amdgcn_ds_swizzle((int)_lo, 0x401f);\
  unsigned int _shi = (unsigned int)__builtin_amdgcn_ds_swizzle((int)_hi, 0x401f);\
  unsigned long long _o = (((unsigned long long)_shi) << 32) | _slo;              \
  if (_o > (v)) (v) = _o;                                                         \
} while (0)

#define SWZ16_MIN64(v) do {                                                       \
  unsigned int _lo = (unsigned int)(v), _hi = (unsigned int)((v) >> 32);          \
  unsigned int _slo = (unsigned int)__builtin_amdgcn_ds_swizzle((int)_lo, 0x401f);\
  unsigned int _shi = (unsigned int)__builtin_amdgcn_ds_swizzle((int)_hi, 0x401f);\
  unsigned long long _o = (((unsigned long long)_shi) << 32) | _slo;              \
  if (_o < (v)) (v) = _o;                                                         \
} while (0)

#define SHF32_MAX64(v) do {                                                       \
  unsigned long long _o = __shfl_xor((v), 32, 64);                                \
  if (_o > (v)) (v) = _o;                                                         \
} while (0)

#define SHF32_MIN64(v) do {                                                       \
  unsigned long long _o = __shfl_xor((v), 32, 64);                                \
  if (_o < (v)) (v) = _o;                                                         \
} while (0)

// ---------------- FPS: one block per batch, 511 serial argmax steps ----------
__global__ __launch_bounds__(FT) void fps_kernel(const float* __restrict__ pts,
                                                 int* __restrict__ fps_idx) {
  const int b = blockIdx.x;
  const int tid = threadIdx.x;
  const float* __restrict__ px = pts + (size_t)b * 3 * NPTS;
  const float* __restrict__ py = px + NPTS;
  const float* __restrict__ pz = py + NPTS;

  float x[FPPT], y[FPPT], z[FPPT], dist[FPPT];
#pragma unroll
  for (int k = 0; k < FPPT; ++k) {
    const int i = tid + k * FT;
    x[k] = px[i]; y[k] = py[i]; z[k] = pz[i];
    dist[k] = 1e10f;
  }
  __shared__ unsigned long long waveres[2][16];  // parity double-buffer -> 1 barrier/step
  if (tid == 0) fps_idx[b * FPS_N] = 0;
  float bx = px[0], by = py[0], bz = pz[0];

  for (int step = 1; step < FPS_N; ++step) {
    // per-thread best: float dist + small-int slot (inline-const cndmask)
    float bd = -1.0f;
    int bk = 0;
#pragma unroll
    for (int k = 0; k < FPPT; ++k) {
      // match numpy/jax: (x-c)**2 summed, no fma contraction
      const float dx = __fsub_rn(x[k], bx);
      const float dy = __fsub_rn(y[k], by);
      const float dz = __fsub_rn(z[k], bz);
      const float d = __fadd_rn(__fadd_rn(__fmul_rn(dx, dx), __fmul_rn(dy, dy)),
                                __fmul_rn(dz, dz));
      const float dk = fminf(dist[k], d);
      dist[k] = dk;
      if (dk > bd) { bd = dk; bk = k; }  // strict > : lowest k (lowest idx) on ties
    }
    const uint32_t bi = (uint32_t)tid + ((uint32_t)bk << 10);
    unsigned long long key =
        ((unsigned long long)__float_as_uint(bd) << 32) | (uint32_t)(~bi);

    // intra-wave 64-lane max: 4 DPP row steps + xor16 swizzle + xor32 shuffle
    DPP_MAX64(key, CTRL_XOR1);
    DPP_MAX64(key, CTRL_XOR2);
    DPP_MAX64(key, CTRL_ROR4);
    DPP_MAX64(key, CTRL_ROR8);
    SWZ16_MAX64(key);
    SHF32_MAX64(key);

    const int par = step & 1;
    if ((tid & 63) == 0) waveres[par][tid >> 6] = key;
    __syncthreads();

    // lane-parallel 16-way reduce: each lane reads one partial, 4 DPP steps
    unsigned long long g = waveres[par][tid & 15];
    DPP_MAX64(g, CTRL_XOR1);
    DPP_MAX64(g, CTRL_XOR2);
    DPP_MAX64(g, CTRL_ROR4);
    DPP_MAX64(g, CTRL_ROR8);

    const uint32_t widx = ~(uint32_t)g;
    if (tid == 0) fps_idx[b * FPS_N + step] = (int)widx;
    bx = px[widx]; by = py[widx]; bz = pz[widx];  // broadcast (L1/L2-hot)
  }
}

// ---------------- ball-radius counts for the 50 anchors ---------------------
__global__ __launch_bounds__(256) void count_kernel(const float* __restrict__ pts,
                                                    const int* __restrict__ fps_idx,
                                                    int* __restrict__ counts) {
  const int b = blockIdx.y, a = blockIdx.x;
  const int tid = threadIdx.x;
  const float* __restrict__ px = pts + (size_t)b * 3 * NPTS;
  const float* __restrict__ py = px + NPTS;
  const float* __restrict__ pz = py + NPTS;
  const int aidx = fps_idx[b * FPS_N + a];
  const float ax = px[aidx], ay = py[aidx], az = pz[aidx];
  const float asum = __fadd_rn(__fadd_rn(__fmul_rn(ax, ax), __fmul_rn(ay, ay)),
                               __fmul_rn(az, az));
  const float R2 = (float)(0.4 * 0.4);
  int cnt = 0;
  for (int i = tid; i < NPTS; i += 256) {
    const float X = px[i], Y = py[i], Z = pz[i];
    const float dot = __fadd_rn(__fadd_rn(__fmul_rn(ax, X), __fmul_rn(ay, Y)),
                                __fmul_rn(az, Z));
    const float psum = __fadd_rn(__fadd_rn(__fmul_rn(X, X), __fmul_rn(Y, Y)),
                                 __fmul_rn(Z, Z));
    const float d = __fadd_rn(__fadd_rn(__fmul_rn(-2.0f, dot), asum), psum);
    cnt += (d < R2) ? 1 : 0;
  }
#pragma unroll
  for (int off = 32; off > 0; off >>= 1) cnt += __shfl_xor(cnt, off, 64);
  __shared__ int ws[4];
  if ((tid & 63) == 0) ws[tid >> 6] = cnt;
  __syncthreads();
  if (tid == 0) {
    int c = ws[0] + ws[1] + ws[2] + ws[3];
    counts[b * NANCH + a] = c < BALLK ? c : BALLK;
  }
}

// ---------------- top-4 anchors by count (ties -> lowest anchor index) ------
__global__ void top4_kernel(const int* __restrict__ counts,
                            const int* __restrict__ fps_idx,
                            int* __restrict__ top4pt) {
  const int b = threadIdx.x;
  if (b >= BATCH) return;
  unsigned long long used = 0ULL;
  for (int r = 0; r < TOPK; ++r) {
    int bestc = -1, besta = 0;
    for (int a = 0; a < NANCH; ++a) {
      if (used & (1ULL << a)) continue;
      const int c = counts[b * NANCH + a];
      if (c > bestc) { bestc = c; besta = a; }   // strict > keeps lowest index on ties
    }
    used |= 1ULL << besta;
    top4pt[b * TOPK + r] = fps_idx[b * FPS_N + besta];
  }
}

// ---------------- 128-NN per selected anchor, in sorted order ---------------
#define KT 1024
#define KPPT (NPTS / KT)  // 16

__device__ __forceinline__ uint32_t f2key(float f) {
  uint32_t u = __float_as_uint(f);
  return (u & 0x80000000u) ? ~u : (u | 0x80000000u);
}

__global__ __launch_bounds__(KT) void knn_kernel(const float* __restrict__ pts,
                                                 const int* __restrict__ top4pt,
                                                 int* __restrict__ nn_idx) {
  const int b = blockIdx.y, j = blockIdx.x;
  const int tid = threadIdx.x;
  const float* __restrict__ px = pts + (size_t)b * 3 * NPTS;
  const float* __restrict__ py = px + NPTS;
  const float* __restrict__ pz = py + NPTS;
  const int aidx = top4pt[b * TOPK + j];
  const float ax = px[aidx], ay = py[aidx], az = pz[aidx];
  const float asum = __fadd_rn(__fadd_rn(__fmul_rn(ax, ax), __fmul_rn(ay, ay)),
                               __fmul_rn(az, az));
  unsigned long long key[KPPT];
#pragma unroll
  for (int k = 0; k < KPPT; ++k) {
    const int i = tid + k * KT;
    const float X = px[i], Y = py[i], Z = pz[i];
    const float dot = __fadd_rn(__fadd_rn(__fmul_rn(ax, X), __fmul_rn(ay, Y)),
                                __fmul_rn(az, Z));
    const float psum = __fadd_rn(__fadd_rn(__fmul_rn(X, X), __fmul_rn(Y, Y)),
                                 __fmul_rn(Z, Z));
    const float d = __fadd_rn(__fadd_rn(__fmul_rn(-2.0f, dot), asum), psum);
    key[k] = ((unsigned long long)f2key(d) << 32) | (uint32_t)i;  // asc dist, ties asc idx
  }
  __shared__ unsigned long long waveres[2][16];
  for (int t = 0; t < NBH; ++t) {
    // tree-min over the 16 register keys (depth 4, not 15-deep chain)
    unsigned long long m01 = key[0] < key[1] ? key[0] : key[1];
    unsigned long long m23 = key[2] < key[3] ? key[2] : key[3];
    unsigned long long m45 = key[4] < key[5] ? key[4] : key[5];
    unsigned long long m67 = key[6] < key[7] ? key[6] : key[7];
    unsigned long long m89 = key[8] < key[9] ? key[8] : key[9];
    unsigned long long mab = key[10] < key[11] ? key[10] : key[11];
    unsigned long long mcd = key[12] < key[13] ? key[12] : key[13];
    unsigned long long mef = key[14] < key[15] ? key[14] : key[15];
    unsigned long long m0 = m01 < m23 ? m01 : m23;
    unsigned long long m1 = m45 < m67 ? m45 : m67;
    unsigned long long m2 = m89 < mab ? m89 : mab;
    unsigned long long m3 = mcd < mef ? mcd : mef;
    unsigned long long ma = m0 < m1 ? m0 : m1;
    unsigned long long mb = m2 < m3 ? m2 : m3;
    unsigned long long m = ma < mb ? ma : mb;

    DPP_MIN64(m, CTRL_XOR1);
    DPP_MIN64(m, CTRL_XOR2);
    DPP_MIN64(m, CTRL_ROR4);
    DPP_MIN64(m, CTRL_ROR8);
    SWZ16_MIN64(m);
    SHF32_MIN64(m);

    const int par = t & 1;
    if ((tid & 63) == 0) waveres[par][tid >> 6] = m;
    __syncthreads();
    unsigned long long g = waveres[par][tid & 15];
    DPP_MIN64(g, CTRL_XOR1);
    DPP_MIN64(g, CTRL_XOR2);
    DPP_MIN64(g, CTRL_ROR4);
    DPP_MIN64(g, CTRL_ROR8);

    if (tid == 0) nn_idx[(b * TOPK + j) * NBH + t] = (int)(uint32_t)g;
#pragma unroll
    for (int k = 0; k < KPPT; ++k)
      if (key[k] == g) key[k] = ~0ULL;  // remove winner (unique low bits)
  }
}

// ---------------- final gather: [roi, roi, fps_pts] -> out [16,1536,3] ------
__global__ __launch_bounds__(512) void gather_kernel(const float* __restrict__ pts,
                                                     const int* __restrict__ nn_idx,
                                                     const int* __restrict__ fps_idx,
                                                     float* __restrict__ out) {
  const int b = blockIdx.x, t = threadIdx.x;
  const float* __restrict__ px = pts + (size_t)b * 3 * NPTS;
  const float* __restrict__ py = px + NPTS;
  const float* __restrict__ pz = py + NPTS;
  for (int s = t; s < 1536; s += 512) {
    int src;
    if (s < 1024) src = nn_idx[b * 512 + (s & 511)];      // roi1 and roi2 identical
    else          src = fps_idx[b * FPS_N + (s - 1024)];
    float* o = out + ((size_t)b * 1536 + s) * 3;
    o[0] = px[src]; o[1] = py[src]; o[2] = pz[src];
  }
}

extern "C" void kernel_launch(void* const* d_in, const int* in_sizes, int n_in,
                              void* d_out, int out_size, void* d_ws, size_t ws_size,
                              hipStream_t stream) {
  const float* pts = (const float*)d_in[0];   // [16, 3, 16384]
  float* out = (float*)d_out;                 // [16, 1536, 3]
  char* ws = (char*)d_ws;
  int* fps_idx = (int*)(ws);            // 16*512*4 = 32768 B
  int* counts  = (int*)(ws + 32768);    // 16*50*4  =  3200 B
  int* top4pt  = (int*)(ws + 40960);    // 16*4*4   =   256 B
  int* nn_idx  = (int*)(ws + 49152);    // 16*512*4 = 32768 B

  fps_kernel<<<dim3(BATCH), dim3(FT), 0, stream>>>(pts, fps_idx);
  count_kernel<<<dim3(NANCH, BATCH), dim3(256), 0, stream>>>(pts, fps_idx, counts);
  top4_kernel<<<dim3(1), dim3(64), 0, stream>>>(counts, fps_idx, top4pt);
  knn_kernel<<<dim3(TOPK, BATCH), dim3(KT), 0, stream>>>(pts, top4pt, nn_idx);
  gather_kernel<<<dim3(BATCH), dim3(512), 0, stream>>>(pts, nn_idx, fps_idx, out);
}